// Round 2
// baseline (1785.580 us; speedup 1.0000x reference)
//
#include <hip/hip_runtime.h>

// RBFNSemanticLayer fused kernel, MI355X (gfx950)
// B=64, P=2048, K=16, DIM=3, NC=16, SFD=64, OUTF=64
//
// out[b,p,o] = sum_s ( fl[b,p,s] * sp[b,p,s] ) * w[b,s,o]
//   fl[b,p,s] = sum_c ( sum_k exp(-|f[b,p,k,:]-C[:,c]|^2/0.08) ) * Wr[c,s]
//   sp[b,p,s] = sum_k spatial[b,p,k,s]
//
// R2: occupancy fix. launch_bounds(256,8) -> 8 blocks/CU (LDS=20480B, VGPR=64
// both fit exactly); 2048 blocks = one full residency round on 256 CUs.
// Grid axes swapped so consecutive blocks stream contiguous HBM within one
// batch and share w[b] in L2. All 28 long-latency loads issued before the
// compute tail of each pass.

#define PP 2048
#define KK 16
#define NC 16
#define SFDIM 64
#define OUTF 64
#define P_PER_BLOCK 64
#define THREADS 256

__global__ __launch_bounds__(THREADS, 8)
void rbfn_fused_kernel(const float* __restrict__ features,
                       const float* __restrict__ spatial,
                       const float* __restrict__ centers,
                       const float* __restrict__ rbfw,
                       const float* __restrict__ w,
                       float* __restrict__ out)
{
    __shared__ float4 lds_w4[SFDIM * OUTF / 4];   // 1024 float4 = 16 KB
    __shared__ float4 lds_wr4[NC * SFDIM / 4];    // 256 float4 = 4 KB

    const int tid = threadIdx.x;
    const int b = blockIdx.y;            // batch
    const int p0 = blockIdx.x * P_PER_BLOCK;  // p-tile (consecutive blocks = contiguous p)

    // ---- stage w[b] (4096 floats) and rbfn_weight (1024 floats) into LDS ----
    const float4* wg4 = (const float4*)(w + (size_t)b * SFDIM * OUTF);
    #pragma unroll
    for (int i = 0; i < 4; ++i)
        lds_w4[tid + i * THREADS] = wg4[tid + i * THREADS];
    lds_wr4[tid] = ((const float4*)rbfw)[tid];
    __syncthreads();

    const int t = tid & 15;        // o4-chunk index / rbf-center index
    const int base = tid & 48;     // 16-lane group base within the wave

    // centers layout (DIM, NC): centers[d*NC + c]; this thread's c == t
    const float C0 = centers[t];
    const float C1 = centers[NC + t];
    const float C2 = centers[2 * NC + t];

    #pragma unroll
    for (int pass = 0; pass < P_PER_BLOCK / 16; ++pass) {
        const int p = p0 + pass * 16 + (tid >> 4);
        const size_t bp = (size_t)b * PP + p;

        // ---- issue ALL long-latency loads up front (28 float4 in flight) ----
        const float4* sp4p = (const float4*)spatial + bp * (KK * SFDIM / 4) + t;
        const float4* f4 = (const float4*)features + bp * 12;   // 48 floats/p

        float4 sv[KK];
        #pragma unroll
        for (int k = 0; k < KK; ++k)
            sv[k] = sp4p[k * (SFDIM / 4)];

        float4 fv[12];
        #pragma unroll
        for (int i = 0; i < 12; ++i)
            fv[i] = f4[i];

        // ---- sp4 = sum_k spatial[b,p,k, 4t..4t+3]  (the 537 MB stream) ----
        float4 sp; sp.x = sp.y = sp.z = sp.w = 0.f;
        #pragma unroll
        for (int k = 0; k < KK; ++k) {
            sp.x += sv[k].x; sp.y += sv[k].y; sp.z += sv[k].z; sp.w += sv[k].w;
        }

        // ---- rbfsum (this thread's c = t): sum_k exp(-dn2/0.08) ----
        float rbfsum = 0.f;
        #define RBF_STEP(FX,FY,FZ) { \
            float dx=(FX)-C0, dy=(FY)-C1, dz=(FZ)-C2; \
            float dn2 = dx*dx + dy*dy + dz*dz; \
            rbfsum += __expf(dn2 * -12.5f); }
        #pragma unroll
        for (int kq = 0; kq < 4; ++kq) {
            float4 a  = fv[kq * 3 + 0];
            float4 bq = fv[kq * 3 + 1];
            float4 cq = fv[kq * 3 + 2];
            RBF_STEP(a.x,  a.y,  a.z);    // k = 4kq+0
            RBF_STEP(a.w,  bq.x, bq.y);   // k = 4kq+1
            RBF_STEP(bq.z, bq.w, cq.x);   // k = 4kq+2
            RBF_STEP(cq.y, cq.z, cq.w);   // k = 4kq+3
        }
        #undef RBF_STEP

        // ---- fl4[o-chunk t] = sum_c rbfsum[c] * Wr[c, 4t..4t+3] ----
        float4 fl; fl.x = fl.y = fl.z = fl.w = 0.f;
        #pragma unroll
        for (int c = 0; c < NC; ++c) {
            float rs = __shfl(rbfsum, base | c, 64);
            float4 wr = lds_wr4[c * 16 + t];
            fl.x += rs * wr.x; fl.y += rs * wr.y;
            fl.z += rs * wr.z; fl.w += rs * wr.w;
        }

        // ---- x = fl * sp ----
        float4 x;
        x.x = fl.x * sp.x; x.y = fl.y * sp.y;
        x.z = fl.z * sp.z; x.w = fl.w * sp.w;

        // ---- out4[o-chunk t] = sum_s x[s] * w[b, s, 4t..4t+3] ----
        float4 o4; o4.x = o4.y = o4.z = o4.w = 0.f;
        #pragma unroll
        for (int sc = 0; sc < 16; ++sc) {
            float xs0 = __shfl(x.x, base | sc, 64);
            float xs1 = __shfl(x.y, base | sc, 64);
            float xs2 = __shfl(x.z, base | sc, 64);
            float xs3 = __shfl(x.w, base | sc, 64);
            float4 w0 = lds_w4[(sc * 4 + 0) * 16 + t];
            float4 w1 = lds_w4[(sc * 4 + 1) * 16 + t];
            float4 w2 = lds_w4[(sc * 4 + 2) * 16 + t];
            float4 w3 = lds_w4[(sc * 4 + 3) * 16 + t];
            o4.x += xs0 * w0.x + xs1 * w1.x + xs2 * w2.x + xs3 * w3.x;
            o4.y += xs0 * w0.y + xs1 * w1.y + xs2 * w2.y + xs3 * w3.y;
            o4.z += xs0 * w0.z + xs1 * w1.z + xs2 * w2.z + xs3 * w3.z;
            o4.w += xs0 * w0.w + xs1 * w1.w + xs2 * w2.w + xs3 * w3.w;
        }

        ((float4*)out)[bp * 16 + t] = o4;
    }
}

extern "C" void kernel_launch(void* const* d_in, const int* in_sizes, int n_in,
                              void* d_out, int out_size, void* d_ws, size_t ws_size,
                              hipStream_t stream) {
    const float* features = (const float*)d_in[0];
    const float* spatial  = (const float*)d_in[1];
    const float* centers  = (const float*)d_in[2];
    const float* rbfw     = (const float*)d_in[3];
    const float* w        = (const float*)d_in[4];
    // d_in[5] is K (==16), hard-coded.
    float* out = (float*)d_out;

    dim3 grid(PP / P_PER_BLOCK, 64);   // (32 p-tiles, 64 batches)
    rbfn_fused_kernel<<<grid, THREADS, 0, stream>>>(
        features, spatial, centers, rbfw, w, out);
}

// Round 3
// 1082.630 us; speedup vs baseline: 1.6493x; 1.6493x over previous
//
#include <hip/hip_runtime.h>

// RBFNSemanticLayer, MI355X (gfx950) — R3: split stream from compute.
// B=64, P=2048, K=16, DIM=3, NC=16, SFD=64, OUTF=64
//
// Kernel 1: sp_sum[b,p,s] = sum_k spatial[b,p,k,s]   (537 MB -> 34 MB, pure BW)
//           written into d_out (same size as final out: B*P*64).
// Kernel 2: out[b,p,o] = sum_s (fl[b,p,s]*sp_sum[b,p,s]) * w[b,s,o]
//           fl[b,p,s] = (sum_k exp(-|f[b,p,k,:]-C[:,c]|^2/.08)) @ Wr
//           reads sp_sum from d_out and overwrites the same addresses
//           (same lane reads then writes its own float4 chunk — no hazard).

#define PP 2048
#define KK 16
#define NC 16
#define SFDIM 64
#define OUTF 64
#define THREADS 256
#define P_PER_BLOCK 64

// ---------------------------------------------------------------- kernel 1
// One thread per output float4. i = bp*16 + chunk. Input row for bp is
// 256 float4 (K*S floats); chunk c reads offsets c, c+16, ..., c+240.
__global__ __launch_bounds__(THREADS)
void spatial_reduce_kernel(const float4* __restrict__ in,
                           float4* __restrict__ sp_sum)
{
    const size_t i = (size_t)blockIdx.x * THREADS + threadIdx.x;
    const float4* src = in + ((i >> 4) << 8) + (i & 15);

    // 4 independent accumulation chains for memory-level parallelism.
    float4 a0 = src[0 * 16], a1 = src[1 * 16], a2 = src[2 * 16], a3 = src[3 * 16];
    #pragma unroll
    for (int k = 4; k < KK; k += 4) {
        float4 v0 = src[(k + 0) * 16];
        float4 v1 = src[(k + 1) * 16];
        float4 v2 = src[(k + 2) * 16];
        float4 v3 = src[(k + 3) * 16];
        a0.x += v0.x; a0.y += v0.y; a0.z += v0.z; a0.w += v0.w;
        a1.x += v1.x; a1.y += v1.y; a1.z += v1.z; a1.w += v1.w;
        a2.x += v2.x; a2.y += v2.y; a2.z += v2.z; a2.w += v2.w;
        a3.x += v3.x; a3.y += v3.y; a3.z += v3.z; a3.w += v3.w;
    }
    float4 r;
    r.x = (a0.x + a1.x) + (a2.x + a3.x);
    r.y = (a0.y + a1.y) + (a2.y + a3.y);
    r.z = (a0.z + a1.z) + (a2.z + a3.z);
    r.w = (a0.w + a1.w) + (a2.w + a3.w);
    sp_sum[i] = r;
}

// ---------------------------------------------------------------- kernel 2
__global__ __launch_bounds__(THREADS)
void rbfn_compute_kernel(const float* __restrict__ features,
                         const float* __restrict__ centers,
                         const float* __restrict__ rbfw,
                         const float* __restrict__ w,
                         float4* io)   // sp_sum in, out out — aliased, no restrict
{
    __shared__ float4 lds_w4[SFDIM * OUTF / 4];   // 16 KB
    __shared__ float4 lds_wr4[NC * SFDIM / 4];    // 4 KB

    const int tid = threadIdx.x;
    const int b = blockIdx.y;
    const int p0 = blockIdx.x * P_PER_BLOCK;

    const float4* wg4 = (const float4*)(w + (size_t)b * SFDIM * OUTF);
    #pragma unroll
    for (int i = 0; i < 4; ++i)
        lds_w4[tid + i * THREADS] = wg4[tid + i * THREADS];
    lds_wr4[tid] = ((const float4*)rbfw)[tid];
    __syncthreads();

    const int t = tid & 15;        // o4-chunk index / rbf-center index
    const int base = tid & 48;     // 16-lane group base within the wave

    const float C0 = centers[t];
    const float C1 = centers[NC + t];
    const float C2 = centers[2 * NC + t];

    #pragma unroll
    for (int pass = 0; pass < P_PER_BLOCK / 16; ++pass) {
        const int p = p0 + pass * 16 + (tid >> 4);
        const size_t bp = (size_t)b * PP + p;

        // single float4 of the pre-reduced spatial sum (from kernel 1)
        float4 sp = io[bp * 16 + t];

        // rbfsum for this thread's center c = t, consumed inline (no arrays)
        const float4* f4 = (const float4*)features + bp * 12;
        float rbfsum = 0.f;
        #define RBF_STEP(FX,FY,FZ) { \
            float dx=(FX)-C0, dy=(FY)-C1, dz=(FZ)-C2; \
            float dn2 = dx*dx + dy*dy + dz*dz; \
            rbfsum += __expf(dn2 * -12.5f); }
        #pragma unroll
        for (int kq = 0; kq < 4; ++kq) {
            float4 a  = f4[kq * 3 + 0];
            float4 bq = f4[kq * 3 + 1];
            float4 cq = f4[kq * 3 + 2];
            RBF_STEP(a.x,  a.y,  a.z);
            RBF_STEP(a.w,  bq.x, bq.y);
            RBF_STEP(bq.z, bq.w, cq.x);
            RBF_STEP(cq.y, cq.z, cq.w);
        }
        #undef RBF_STEP

        // fl4 = sum_c rbfsum[c] * Wr[c, 4t..4t+3]
        float4 fl; fl.x = fl.y = fl.z = fl.w = 0.f;
        #pragma unroll
        for (int c = 0; c < NC; ++c) {
            float rs = __shfl(rbfsum, base | c, 64);
            float4 wr = lds_wr4[c * 16 + t];
            fl.x += rs * wr.x; fl.y += rs * wr.y;
            fl.z += rs * wr.z; fl.w += rs * wr.w;
        }

        // x = fl * sp
        float4 x;
        x.x = fl.x * sp.x; x.y = fl.y * sp.y;
        x.z = fl.z * sp.z; x.w = fl.w * sp.w;

        // o4 = sum_s x[s] * w[b, s, 4t..4t+3]
        float4 o4; o4.x = o4.y = o4.z = o4.w = 0.f;
        #pragma unroll
        for (int sc = 0; sc < 16; ++sc) {
            float xs0 = __shfl(x.x, base | sc, 64);
            float xs1 = __shfl(x.y, base | sc, 64);
            float xs2 = __shfl(x.z, base | sc, 64);
            float xs3 = __shfl(x.w, base | sc, 64);
            float4 w0 = lds_w4[(sc * 4 + 0) * 16 + t];
            float4 w1 = lds_w4[(sc * 4 + 1) * 16 + t];
            float4 w2 = lds_w4[(sc * 4 + 2) * 16 + t];
            float4 w3 = lds_w4[(sc * 4 + 3) * 16 + t];
            o4.x += xs0 * w0.x + xs1 * w1.x + xs2 * w2.x + xs3 * w3.x;
            o4.y += xs0 * w0.y + xs1 * w1.y + xs2 * w2.y + xs3 * w3.y;
            o4.z += xs0 * w0.z + xs1 * w1.z + xs2 * w2.z + xs3 * w3.z;
            o4.w += xs0 * w0.w + xs1 * w1.w + xs2 * w2.w + xs3 * w3.w;
        }

        // overwrite the sp_sum slot this lane read — same lane, same address
        io[bp * 16 + t] = o4;
    }
}

extern "C" void kernel_launch(void* const* d_in, const int* in_sizes, int n_in,
                              void* d_out, int out_size, void* d_ws, size_t ws_size,
                              hipStream_t stream) {
    const float* features = (const float*)d_in[0];
    const float* spatial  = (const float*)d_in[1];
    const float* centers  = (const float*)d_in[2];
    const float* rbfw     = (const float*)d_in[3];
    const float* w        = (const float*)d_in[4];
    float4* io = (float4*)d_out;

    // Kernel 1: reduce spatial over k. 64*2048*16 = 2,097,152 float4 outputs.
    const int n_out4 = 64 * PP * 16;
    spatial_reduce_kernel<<<n_out4 / THREADS, THREADS, 0, stream>>>(
        (const float4*)spatial, io);

    // Kernel 2: RBF + matvecs, in-place on d_out.
    dim3 grid2(PP / P_PER_BLOCK, 64);
    rbfn_compute_kernel<<<grid2, THREADS, 0, stream>>>(
        features, centers, rbfw, w, io);
}